// Round 1
// baseline (359.364 us; speedup 1.0000x reference)
//
#include <hip/hip_runtime.h>

// Problem constants (fixed by reference: pred_vol shape (1,1,64,512,512) fp32)
static constexpr int Dd = 64;
static constexpr int Hh = 512;
static constexpr int Ww = 512;
static constexpr int RAD = 4;          // window = 2*RAD+1 = 9
static constexpr float THRESH_V = 0.5f;
static constexpr int NTOT = Dd * Hh * Ww;   // 16,777,216 (divisible by 256)

__device__ __forceinline__ float thr(float v) {
    return v > THRESH_V ? v : 0.0f;
}

// Pass 1: thresholded max along W (contiguous axis). x -> o
__global__ void wmax_k(const float* __restrict__ x, float* __restrict__ o) {
    int idx = blockIdx.x * 256 + threadIdx.x;
    int w = idx & (Ww - 1);
    int rowbase = idx - w;
    int w0 = w - RAD; if (w0 < 0) w0 = 0;
    int w1 = w + RAD; if (w1 > Ww - 1) w1 = Ww - 1;
    float m = 0.0f;
    for (int ww = w0; ww <= w1; ++ww) m = fmaxf(m, thr(x[rowbase + ww]));
    o[idx] = m;
}

// Pass 2: max along H. in -> o
__global__ void hmax_k(const float* __restrict__ in, float* __restrict__ o) {
    int idx = blockIdx.x * 256 + threadIdx.x;
    int w = idx & (Ww - 1);
    int h = (idx >> 9) & (Hh - 1);
    int base = idx - h * Ww;   // d*H*W + w
    int h0 = h - RAD; if (h0 < 0) h0 = 0;
    int h1 = h + RAD; if (h1 > Hh - 1) h1 = Hh - 1;
    float m = 0.0f;
    for (int hh = h0; hh <= h1; ++hh) m = fmaxf(m, in[base + hh * Ww]);
    o[idx] = m;
}

// Pass 3: max along D, then compare against thresholded center. in + x -> o
__global__ void dmax_cmp_k(const float* __restrict__ in, const float* __restrict__ x,
                           float* __restrict__ o) {
    int idx = blockIdx.x * 256 + threadIdx.x;
    int d = idx >> 18;                 // H*W = 2^18
    int rem = idx & ((1 << 18) - 1);
    int d0 = d - RAD; if (d0 < 0) d0 = 0;
    int d1 = d + RAD; if (d1 > Dd - 1) d1 = Dd - 1;
    float m = 0.0f;
    for (int dd = d0; dd <= d1; ++dd) m = fmaxf(m, in[dd * (Hh * Ww) + rem]);
    float tx = thr(x[idx]);
    // reference: conf = (max > 0 && max == thresh(x)) ? max : 0  (max == tx there)
    o[idx] = (tx > 0.0f && tx == m) ? tx : 0.0f;
}

// Fallback if ws is too small: direct 9^3 window scan (slow but correct).
__global__ void naive_k(const float* __restrict__ x, float* __restrict__ o) {
    int idx = blockIdx.x * 256 + threadIdx.x;
    int w = idx & (Ww - 1);
    int h = (idx >> 9) & (Hh - 1);
    int d = idx >> 18;
    float tx = thr(x[idx]);
    if (tx <= 0.0f) { o[idx] = 0.0f; return; }
    int w0 = max(w - RAD, 0), w1 = min(w + RAD, Ww - 1);
    int h0 = max(h - RAD, 0), h1 = min(h + RAD, Hh - 1);
    int d0 = max(d - RAD, 0), d1 = min(d + RAD, Dd - 1);
    float m = 0.0f;
    for (int dd = d0; dd <= d1; ++dd)
        for (int hh = h0; hh <= h1; ++hh) {
            int base = dd * (Hh * Ww) + hh * Ww;
            for (int ww = w0; ww <= w1; ++ww)
                m = fmaxf(m, thr(x[base + ww]));
        }
    o[idx] = (tx == m) ? tx : 0.0f;
}

extern "C" void kernel_launch(void* const* d_in, const int* in_sizes, int n_in,
                              void* d_out, int out_size, void* d_ws, size_t ws_size,
                              hipStream_t stream) {
    const float* x = (const float*)d_in[0];
    float* out = (float*)d_out;
    float* ws = (float*)d_ws;

    dim3 block(256);
    dim3 grid(NTOT / 256);   // exact: 65536 blocks

    if (ws_size >= (size_t)NTOT * sizeof(float)) {
        // pass1: x -> out (W-max of thresholded)
        wmax_k<<<grid, block, 0, stream>>>(x, out);
        // pass2: out -> ws (H-max)
        hmax_k<<<grid, block, 0, stream>>>(out, ws);
        // pass3: ws + x -> out (D-max + local-max compare)
        dmax_cmp_k<<<grid, block, 0, stream>>>(ws, x, out);
    } else {
        naive_k<<<grid, block, 0, stream>>>(x, out);
    }
}

// Round 2
// 166.074 us; speedup vs baseline: 2.1639x; 2.1639x over previous
//
#include <hip/hip_runtime.h>

// pred_vol shape (1,1,64,512,512) fp32; threshold 0.5; window 9 (R=4)
static constexpr int Dd = 64;
static constexpr int Hh = 512;
static constexpr int Ww = 512;
static constexpr int RAD = 4;
static constexpr float THRESH_V = 0.5f;
static constexpr int NTOT = Dd * Hh * Ww;        // 16,777,216
static constexpr int W4 = Ww / 4;                // 128 float4 per row
static constexpr int PLANE4 = Hh * W4;           // 65536 float4 per D-plane

__device__ __forceinline__ float thr(float v) { return v > THRESH_V ? v : 0.0f; }

__device__ __forceinline__ float4 f4max(float4 a, float4 b) {
    return make_float4(fmaxf(a.x, b.x), fmaxf(a.y, b.y), fmaxf(a.z, b.z), fmaxf(a.w, b.w));
}
__device__ __forceinline__ float4 thr4(float4 v) {
    return make_float4(thr(v.x), thr(v.y), thr(v.z), thr(v.w));
}

// ---------------- Pass 1: threshold + max along W ----------------
// One thread -> one float4 of outputs. 3 float4 loads cover all four 9-windows.
__global__ void wmax4_k(const float4* __restrict__ x4, float4* __restrict__ o4) {
    int idx = blockIdx.x * 256 + threadIdx.x;       // NTOT/4 threads
    int c = idx & (W4 - 1);
    int rowbase = idx - c;
    float4 v0 = x4[rowbase + (c > 0 ? c - 1 : 0)];
    float4 v1 = x4[idx];
    float4 v2 = x4[rowbase + (c < W4 - 1 ? c + 1 : W4 - 1)];
    v0 = thr4(v0); v1 = thr4(v1); v2 = thr4(v2);
    float a0 = v0.x, a1 = v0.y, a2 = v0.z, a3 = v0.w;
    float a4 = v1.x, a5 = v1.y, a6 = v1.z, a7 = v1.w;
    float a8 = v2.x, a9 = v2.y, a10 = v2.z, a11 = v2.w;
    // suffix maxes of left block, prefix maxes of right block, core of middle
    float l3 = a3, l2 = fmaxf(a2, l3), l1 = fmaxf(a1, l2), l0 = fmaxf(a0, l1);
    float core = fmaxf(fmaxf(a4, a5), fmaxf(a6, a7));
    float r8 = a8, r9 = fmaxf(r8, a9), r10 = fmaxf(r9, a10), r11 = fmaxf(r10, a11);
    float4 o;
    o.x = fmaxf(l0, fmaxf(core, r8));
    o.y = fmaxf(l1, fmaxf(core, r9));
    o.z = fmaxf(l2, fmaxf(core, r10));
    o.w = fmaxf(l3, fmaxf(core, r11));
    o4[idx] = o;
}

// ---------------- Pass 2: max along H ----------------
// One thread -> 8 consecutive h outputs (one float4 wide). 16 loads, 8 stores.
__global__ void hmax4_k(const float4* __restrict__ in4, float4* __restrict__ o4) {
    int idx = blockIdx.x * 256 + threadIdx.x;       // NTOT/4/8 threads
    int c = idx & (W4 - 1);
    int hg = (idx >> 7) & 63;                        // 512/8 = 64 h-groups
    int d = idx >> 13;
    int plane = d * PLANE4;
    int h0 = hg << 3;
    float4 a[16];
#pragma unroll
    for (int k = 0; k < 16; ++k) {
        int h = h0 + k - RAD;
        h = h < 0 ? 0 : (h > Hh - 1 ? Hh - 1 : h);
        a[k] = in4[plane + (h << 7) + c];
    }
    float4 b[15];
#pragma unroll
    for (int k = 0; k < 15; ++k) b[k] = f4max(a[k], a[k + 1]);
    float4 q[12];
#pragma unroll
    for (int k = 0; k < 12; ++k) q[k] = f4max(b[k], b[k + 2]);  // max(a[k..k+3])
#pragma unroll
    for (int j = 0; j < 8; ++j) {
        float4 m = f4max(f4max(q[j], q[j + 4]), a[j + 8]);       // max(a[j..j+8])
        o4[plane + ((h0 + j) << 7) + c] = m;
    }
}

// ---------------- Pass 3: max along D + local-max compare ----------------
__global__ void dmax4_k(const float4* __restrict__ in4, const float4* __restrict__ x4,
                        float4* __restrict__ o4) {
    int idx = blockIdx.x * 256 + threadIdx.x;       // NTOT/4/8 threads
    int p = idx & (PLANE4 - 1);
    int dg = idx >> 16;                              // 64/8 = 8 d-groups
    int d0 = dg << 3;
    float4 a[16];
#pragma unroll
    for (int k = 0; k < 16; ++k) {
        int d = d0 + k - RAD;
        d = d < 0 ? 0 : (d > Dd - 1 ? Dd - 1 : d);
        a[k] = in4[d * PLANE4 + p];
    }
    float4 b[15];
#pragma unroll
    for (int k = 0; k < 15; ++k) b[k] = f4max(a[k], a[k + 1]);
    float4 q[12];
#pragma unroll
    for (int k = 0; k < 12; ++k) q[k] = f4max(b[k], b[k + 2]);
#pragma unroll
    for (int j = 0; j < 8; ++j) {
        float4 m = f4max(f4max(q[j], q[j + 4]), a[j + 8]);
        float4 tx = thr4(x4[(d0 + j) * PLANE4 + p]);
        float4 r;
        r.x = (tx.x > 0.0f && tx.x == m.x) ? tx.x : 0.0f;
        r.y = (tx.y > 0.0f && tx.y == m.y) ? tx.y : 0.0f;
        r.z = (tx.z > 0.0f && tx.z == m.z) ? tx.z : 0.0f;
        r.w = (tx.w > 0.0f && tx.w == m.w) ? tx.w : 0.0f;
        o4[(d0 + j) * PLANE4 + p] = r;
    }
}

// ---------------- Fallback (ws too small): direct 9^3 scan ----------------
__global__ void naive_k(const float* __restrict__ x, float* __restrict__ o) {
    int idx = blockIdx.x * 256 + threadIdx.x;
    int w = idx & (Ww - 1);
    int h = (idx >> 9) & (Hh - 1);
    int d = idx >> 18;
    float tx = thr(x[idx]);
    if (tx <= 0.0f) { o[idx] = 0.0f; return; }
    int w0 = max(w - RAD, 0), w1 = min(w + RAD, Ww - 1);
    int h0 = max(h - RAD, 0), h1 = min(h + RAD, Hh - 1);
    int d0 = max(d - RAD, 0), d1 = min(d + RAD, Dd - 1);
    float m = 0.0f;
    for (int dd = d0; dd <= d1; ++dd)
        for (int hh = h0; hh <= h1; ++hh) {
            int base = dd * (Hh * Ww) + hh * Ww;
            for (int ww = w0; ww <= w1; ++ww)
                m = fmaxf(m, thr(x[base + ww]));
        }
    o[idx] = (tx == m) ? tx : 0.0f;
}

extern "C" void kernel_launch(void* const* d_in, const int* in_sizes, int n_in,
                              void* d_out, int out_size, void* d_ws, size_t ws_size,
                              hipStream_t stream) {
    const float* x = (const float*)d_in[0];
    float* out = (float*)d_out;
    float* ws = (float*)d_ws;

    if (ws_size >= (size_t)NTOT * sizeof(float)) {
        const float4* x4 = (const float4*)x;
        float4* out4 = (float4*)out;
        float4* ws4 = (float4*)ws;
        // pass1: x -> out (threshold + W-max), NTOT/4 threads
        wmax4_k<<<dim3(NTOT / 4 / 256), dim3(256), 0, stream>>>(x4, out4);
        // pass2: out -> ws (H-max), NTOT/32 threads
        hmax4_k<<<dim3(NTOT / 32 / 256), dim3(256), 0, stream>>>(out4, ws4);
        // pass3: ws + x -> out (D-max + compare), NTOT/32 threads
        dmax4_k<<<dim3(NTOT / 32 / 256), dim3(256), 0, stream>>>(ws4, x4, out4);
    } else {
        naive_k<<<dim3(NTOT / 256), dim3(256), 0, stream>>>(x, out);
    }
}